// Round 3
// baseline (164.407 us; speedup 1.0000x reference)
//
#include <hip/hip_runtime.h>

// pixelSNAIL causal attention, MI355X gfx950.
// B=32, N=1024, C=128, CM=256, fp32 in/out.
// softmax over FULL row, strict causal mask, then @V.
// R4: prep_kernel: coalesced global IO + LDS transpose (XOR-swizzled slots).
// R5: swapped QK^T (mfma(K,Q)) -> P lane-local; in-register P->A-frag via
//     cvt_pk_bf16 + permlane32/16_swap; K and V double-buffered, prefetched
//     one tile ahead, counted vmcnt(8/4/0).
// R6: 2x operand reuse: BM=128, each wave owns 32 q-rows (two 16-row MFMA
//     groups). Every K/V LDS fragment read feeds 2 MFMAs -> LDS-read traffic
//     per CU halves; grid 256 = 1 block/CU -> staging traffic per CU halves,
//     and all 8 qt-blocks of a batch map to one XCD (bat%8) for L2 reuse.
//     Sync schedule identical to R5.

typedef __attribute__((ext_vector_type(8))) short short8;
typedef __attribute__((ext_vector_type(4))) float floatx4;

#define MFMA16(a, b, c) __builtin_amdgcn_mfma_f32_16x16x32_bf16((a), (b), (c), 0, 0, 0)

constexpr int N = 1024, C = 128, CM = 256, BATCH = 32;
constexpr int BM = 128;            // q rows per block (4 waves x 32 rows)
constexpr int BN = 32;             // keys per tile
constexpr int NT = N / BN;         // 32 tiles
constexpr int KFRAG = BN * C;      // 4096 bf16 per K tile (hi or lo)
constexpr int VFRAG = BN * CM;     // 8192 bf16 per V tile

__device__ __forceinline__ unsigned short f2bf(float x) {
    unsigned int u = __float_as_uint(x);
    u += 0x7fffu + ((u >> 16) & 1u);   // RNE
    return (unsigned short)(u >> 16);
}
__device__ __forceinline__ float bf2f(unsigned short h) {
    return __uint_as_float(((unsigned int)h) << 16);
}
__device__ __forceinline__ uint2 pack4(const unsigned short* s) {
    uint2 u;
    u.x = (unsigned)s[0] | ((unsigned)s[1] << 16);
    u.y = (unsigned)s[2] | ((unsigned)s[3] << 16);
    return u;
}
__device__ __forceinline__ void gl2lds16(const unsigned short* g, unsigned short* l) {
    __builtin_amdgcn_global_load_lds(
        (const __attribute__((address_space(1))) void*)g,
        (__attribute__((address_space(3))) void*)l, 16, 0, 0);
}

// ---------------- prepass: coalesced global IO, LDS transpose ----------------
// Output layouts (consumed by attn_kernel):
//  khi/klo chunk ch in [0,512):  rr=ch&15, qq=(ch>>4)&3, ks=(ch>>6)&3, t=ch>>8
//    khb[ch*8+j] = bf16hi(K[n0 + t*16 + rr][ks*32 + qq*8 + j])
//  vf chunk ch in [0,1024):      rr=ch&15, qq=(ch>>4)&3, ct=ch>>6
//    vfb[ch*8+j] = bf16(V[n0 + qq*8 + j][ct*16 + rr])
__global__ __launch_bounds__(256, 4)
void prep_kernel(const float* __restrict__ kg, const float* __restrict__ vg,
                 unsigned short* __restrict__ khi, unsigned short* __restrict__ klo,
                 unsigned short* __restrict__ vf)
{
    __shared__ __align__(16) unsigned short sKh[KFRAG];   // 8 KB
    __shared__ __align__(16) unsigned short sKl[KFRAG];   // 8 KB
    __shared__ __align__(16) unsigned short sV[VFRAG];    // 16 KB

    const int tid = threadIdx.x;
    const int l = tid & 63, w = tid >> 6;
    const int tile = blockIdx.x, bat = blockIdx.y;
    const int n0 = tile * BN;
    const float* kb = kg + ((size_t)bat * N + n0) * C;
    const float* vb = vg + ((size_t)bat * N + n0) * CM;

    // ---- K staging: contiguous float4 reads (1 KB/instr/wave) ----
#pragma unroll
    for (int it = 0; it < 4; ++it) {
        const int lin = tid + it * 256;
        const float4 x = *(const float4*)(kb + (size_t)lin * 4);
        const int cr = lin >> 1, h = lin & 1;
        const int slot = cr ^ ((cr >> 4) & 7);
        float xs[4] = {x.x, x.y, x.z, x.w};
        unsigned short hi[4], lo[4];
#pragma unroll
        for (int e = 0; e < 4; ++e) {
            unsigned short hb = f2bf(xs[e]);
            hi[e] = hb;
            lo[e] = f2bf(xs[e] - bf2f(hb));
        }
        *(uint2*)(&sKh[slot * 8 + h * 4]) = pack4(hi);
        *(uint2*)(&sKl[slot * 8 + h * 4]) = pack4(lo);
    }

    // ---- V staging: 4 contiguous row-segment float4 reads per group ----
#pragma unroll
    for (int g = 0; g < 2; ++g) {
        const int k0 = g * 16 + w * 4;
        float xa[4][4];   // [e][d] = V[k0+d][4l+e]
#pragma unroll
        for (int d = 0; d < 4; ++d) {
            const float4 t = *(const float4*)(vb + (size_t)(k0 + d) * CM + l * 4);
            xa[0][d] = t.x; xa[1][d] = t.y; xa[2][d] = t.z; xa[3][d] = t.w;
        }
        const int qq = k0 >> 3, j0 = k0 & 7;
#pragma unroll
        for (int e = 0; e < 4; ++e) {
            const int cm = l * 4 + e;
            const int ct = cm >> 4, rr = cm & 15;
            const int ch = ct * 64 + qq * 16 + rr;
            const int slot = ch ^ ((ch >> 6) & 15);
            unsigned short o[4];
#pragma unroll
            for (int d = 0; d < 4; ++d) o[d] = f2bf(xa[e][d]);
            *(uint2*)(&sV[slot * 8 + j0]) = pack4(o);
        }
    }

    __syncthreads();

    unsigned short* khb = khi + ((size_t)bat * NT + tile) * KFRAG;
    unsigned short* klb = klo + ((size_t)bat * NT + tile) * KFRAG;
    unsigned short* vfb = vf + ((size_t)bat * NT + tile) * VFRAG;

    // ---- K out: linear b128 LDS reads, coalesced 16 B/lane global stores ----
#pragma unroll
    for (int it = 0; it < 2; ++it) {
        const int oc = tid + it * 256;
        const int cr = ((oc & 15) + ((oc >> 8) << 4)) * 16 + ((oc >> 6) & 3) * 4 + ((oc >> 4) & 3);
        const int slot = cr ^ ((cr >> 4) & 7);
        *(uint4*)(khb + (size_t)oc * 8) = *(const uint4*)(&sKh[slot * 8]);
        *(uint4*)(klb + (size_t)oc * 8) = *(const uint4*)(&sKl[slot * 8]);
    }
    // ---- V out ----
#pragma unroll
    for (int it = 0; it < 4; ++it) {
        const int oc = tid + it * 256;
        const int slot = oc ^ ((oc >> 6) & 15);
        *(uint4*)(vfb + (size_t)oc * 8) = *(const uint4*)(&sV[slot * 8]);
    }
}

// ---------------- main attention kernel ----------------
__global__ __launch_bounds__(256, 1)
void attn_kernel(const float* __restrict__ qg, float* __restrict__ og,
                 const unsigned short* __restrict__ khi,
                 const unsigned short* __restrict__ klo,
                 const unsigned short* __restrict__ vf)
{
    __shared__ __align__(16) unsigned short sKhi[2][KFRAG];  // 16 KB dbuf
    __shared__ __align__(16) unsigned short sKlo[2][KFRAG];  // 16 KB dbuf
    __shared__ __align__(16) unsigned short sV[2][VFRAG];    // 32 KB dbuf

    const int tid = threadIdx.x;
    const int w = tid >> 6, ln = tid & 63;
    const int r = ln & 15, qd = ln >> 4;
    const int bat = blockIdx.x;   // all 8 qt-blocks of a batch: linear%8 = bat%8 -> one XCD
    const int qt = blockIdx.y;
    const int q0 = qt * BM;
    const int wrow0 = q0 + w * 32;          // this wave's 32 rows

    const float* qb = qg + (size_t)bat * N * C;
    float* ob = og + (size_t)bat * N * CM;
    const unsigned short* khb = khi + (size_t)bat * NT * KFRAG;
    const unsigned short* klb = klo + (size_t)bat * NT * KFRAG;
    const unsigned short* vfb = vf + (size_t)bat * NT * VFRAG;

    // Q fragments for the wave's 2 row-groups (wrow0 + g*16 + r), hi/lo split
    short8 qhi[2][4], qlo[2][4];
#pragma unroll
    for (int g = 0; g < 2; ++g) {
        const float* qr = qb + (size_t)(wrow0 + g * 16 + r) * C + qd * 8;
#pragma unroll
        for (int ks = 0; ks < 4; ++ks) {
            float4 a = *(const float4*)(qr + ks * 32);
            float4 b = *(const float4*)(qr + ks * 32 + 4);
            float xs[8] = {a.x, a.y, a.z, a.w, b.x, b.y, b.z, b.w};
            short8 h, l;
#pragma unroll
            for (int j = 0; j < 8; ++j) {
                unsigned short hb = f2bf(xs[j]);
                h[j] = (short)hb;
                l[j] = (short)f2bf(xs[j] - bf2f(hb));
            }
            qhi[g][ks] = h;
            qlo[g][ks] = l;
        }
    }

    floatx4 oacc[2][16];
#pragma unroll
    for (int g = 0; g < 2; ++g)
#pragma unroll
        for (int ct = 0; ct < 16; ++ct) oacc[g][ct] = (floatx4){0.f, 0.f, 0.f, 0.f};
    float lsum[2] = {0.f, 0.f};
    const int qrow0 = wrow0 + r;            // g=0 row of this lane
    const int qrow1 = wrow0 + 16 + r;       // g=1 row

    // prologue: prefetch K(0) + V(0) into buffer 0 (8 loads/thread)
    gl2lds16(khb + (size_t)tid * 8,         &sKhi[0][tid * 8]);
    gl2lds16(khb + (size_t)(tid + 256) * 8, &sKhi[0][(tid + 256) * 8]);
    gl2lds16(klb + (size_t)tid * 8,         &sKlo[0][tid * 8]);
    gl2lds16(klb + (size_t)(tid + 256) * 8, &sKlo[0][(tid + 256) * 8]);
#pragma unroll
    for (int i = 0; i < 4; ++i)
        gl2lds16(vfb + (size_t)(tid + i * 256) * 8, &sV[0][(tid + i * 256) * 8]);

    for (int tile = 0; tile < NT; ++tile) {
        const bool pvt = (tile <= 4 * qt + 3);   // tile holds keys < some row in block
        const int cb = tile & 1;

        // prefetch K(t+1) (+ V(t+1) if needed); counted vmcnt leaves exactly
        // the just-issued loads in flight across the barrier.
        if (tile + 1 < NT) {
            const unsigned short* k1 = khb + (size_t)(tile + 1) * KFRAG;
            const unsigned short* l1 = klb + (size_t)(tile + 1) * KFRAG;
            unsigned short* dh = &sKhi[cb ^ 1][0];
            unsigned short* dl = &sKlo[cb ^ 1][0];
            gl2lds16(k1 + (size_t)tid * 8,         dh + tid * 8);
            gl2lds16(k1 + (size_t)(tid + 256) * 8, dh + (tid + 256) * 8);
            gl2lds16(l1 + (size_t)tid * 8,         dl + tid * 8);
            gl2lds16(l1 + (size_t)(tid + 256) * 8, dl + (tid + 256) * 8);
            if (tile + 1 <= 4 * qt + 3) {        // V(t+1) needed
                const unsigned short* vs = vfb + (size_t)(tile + 1) * VFRAG;
                unsigned short* dv = &sV[cb ^ 1][0];
#pragma unroll
                for (int i = 0; i < 4; ++i)
                    gl2lds16(vs + (size_t)(tid + i * 256) * 8, dv + (tid + i * 256) * 8);
                asm volatile("s_waitcnt vmcnt(8)" ::: "memory");   // drain K(t)+V(t)
            } else {
                asm volatile("s_waitcnt vmcnt(4)" ::: "memory");   // drain K(t)(+V(t))
            }
        } else {
            asm volatile("s_waitcnt vmcnt(0)" ::: "memory");
        }
        asm volatile("s_barrier" ::: "memory");   // all waves' K(t)/V(t) staged

        // ---- swapped QK^T bf16x3: D[key][qrow], shared K-frag feeds 2 groups ----
        float pk0[8], pk1[8];
#pragma unroll
        for (int t = 0; t < 2; ++t) {
            floatx4 a00 = (floatx4){0.f,0.f,0.f,0.f}, a01 = a00, a02 = a00;
            floatx4 a10 = a00, a11 = a00, a12 = a00;
#pragma unroll
            for (int ks = 0; ks < 4; ++ks) {
                short8 bh = *(const short8*)(&sKhi[cb][(((t * 4 + ks) * 64) + ln) * 8]);
                short8 bl = *(const short8*)(&sKlo[cb][(((t * 4 + ks) * 64) + ln) * 8]);
                a00 = MFMA16(bh, qhi[0][ks], a00);
                a10 = MFMA16(bh, qhi[1][ks], a10);
                a01 = MFMA16(bh, qlo[0][ks], a01);
                a11 = MFMA16(bh, qlo[1][ks], a11);
                a02 = MFMA16(bl, qhi[0][ks], a02);
                a12 = MFMA16(bl, qhi[1][ks], a12);
            }
            const int kbase = tile * BN + t * 16 + qd * 4;
#pragma unroll
            for (int rg = 0; rg < 4; ++rg) {
                float s0 = a00[rg] + a01[rg] + a02[rg];
                float p0 = __expf(s0 - 40.0f);
                lsum[0] += p0;
                pk0[t * 4 + rg] = (kbase + rg < qrow0) ? p0 : 0.0f;
                float s1 = a10[rg] + a11[rg] + a12[rg];
                float p1 = __expf(s1 - 40.0f);
                lsum[1] += p1;
                pk1[t * 4 + rg] = (kbase + rg < qrow1) ? p1 : 0.0f;
            }
        }

        // ---- PV: P->A-frag in-register (cvt_pk + permlane); shared V-frag ----
        if (pvt) {
            unsigned int w00, w01, w02, w03, w10, w11, w12, w13;
            asm("v_cvt_pk_bf16_f32 %0, %1, %2" : "=v"(w00) : "v"(pk0[0]), "v"(pk0[1]));
            asm("v_cvt_pk_bf16_f32 %0, %1, %2" : "=v"(w01) : "v"(pk0[2]), "v"(pk0[3]));
            asm("v_cvt_pk_bf16_f32 %0, %1, %2" : "=v"(w02) : "v"(pk0[4]), "v"(pk0[5]));
            asm("v_cvt_pk_bf16_f32 %0, %1, %2" : "=v"(w03) : "v"(pk0[6]), "v"(pk0[7]));
            asm("v_permlane32_swap_b32 %0, %1" : "+v"(w00), "+v"(w02));
            asm("v_permlane16_swap_b32 %0, %1" : "+v"(w00), "+v"(w02));
            asm("v_permlane32_swap_b32 %0, %1" : "+v"(w01), "+v"(w03));
            asm("v_permlane16_swap_b32 %0, %1" : "+v"(w01), "+v"(w03));
            asm("v_cvt_pk_bf16_f32 %0, %1, %2" : "=v"(w10) : "v"(pk1[0]), "v"(pk1[1]));
            asm("v_cvt_pk_bf16_f32 %0, %1, %2" : "=v"(w11) : "v"(pk1[2]), "v"(pk1[3]));
            asm("v_cvt_pk_bf16_f32 %0, %1, %2" : "=v"(w12) : "v"(pk1[4]), "v"(pk1[5]));
            asm("v_cvt_pk_bf16_f32 %0, %1, %2" : "=v"(w13) : "v"(pk1[6]), "v"(pk1[7]));
            asm("v_permlane32_swap_b32 %0, %1" : "+v"(w10), "+v"(w12));
            asm("v_permlane16_swap_b32 %0, %1" : "+v"(w10), "+v"(w12));
            asm("v_permlane32_swap_b32 %0, %1" : "+v"(w11), "+v"(w13));
            asm("v_permlane16_swap_b32 %0, %1" : "+v"(w11), "+v"(w13));
            uint4 apu0 = make_uint4(w00, w01, w02, w03);
            uint4 apu1 = make_uint4(w10, w11, w12, w13);
            short8 ap0 = *(const short8*)&apu0;
            short8 ap1 = *(const short8*)&apu1;
#pragma unroll
            for (int ct = 0; ct < 16; ++ct) {
                short8 bv = *(const short8*)(&sV[cb][(ct * 64 + ln) * 8]);
                oacc[0][ct] = MFMA16(ap0, bv, oacc[0][ct]);
                oacc[1][ct] = MFMA16(ap1, bv, oacc[1][ct]);
            }
        }
        asm volatile("s_barrier" ::: "memory");   // readers done before next overwrite
    }

    // ---- denominator: reduce across the 4 qd groups (lane owns rows qrow0/1) ----
    float vt0 = lsum[0], vt1 = lsum[1];
    vt0 += __shfl_xor(vt0, 16);
    vt0 += __shfl_xor(vt0, 32);
    vt1 += __shfl_xor(vt1, 16);
    vt1 += __shfl_xor(vt1, 32);

    // ---- divide + store per group ----
#pragma unroll
    for (int rg = 0; rg < 4; ++rg) {
        float inv0 = 1.0f / __shfl(vt0, qd * 4 + rg);   // lane qd*4+rg holds that row's denom
        float inv1 = 1.0f / __shfl(vt1, qd * 4 + rg);
        float* orow0 = ob + (size_t)(wrow0 + qd * 4 + rg) * CM;
        float* orow1 = ob + (size_t)(wrow0 + 16 + qd * 4 + rg) * CM;
#pragma unroll
        for (int ct = 0; ct < 16; ++ct) {
            orow0[ct * 16 + r] = oacc[0][ct][rg] * inv0;
            orow1[ct * 16 + r] = oacc[1][ct][rg] * inv1;
        }
    }
}

extern "C" void kernel_launch(void* const* d_in, const int* in_sizes, int n_in,
                              void* d_out, int out_size, void* d_ws, size_t ws_size,
                              hipStream_t stream) {
    const float* q = (const float*)d_in[0];
    const float* k = (const float*)d_in[1];
    const float* v = (const float*)d_in[2];
    float* o = (float*)d_out;
    (void)n_in; (void)in_sizes; (void)out_size; (void)ws_size;

    unsigned short* khi = (unsigned short*)d_ws;                       // 8 MB
    unsigned short* klo = khi + (size_t)BATCH * NT * KFRAG;            // 8 MB
    unsigned short* vf  = klo + (size_t)BATCH * NT * KFRAG;            // 16 MB

    prep_kernel<<<dim3(NT, BATCH), dim3(256), 0, stream>>>(k, v, khi, klo, vf);
    attn_kernel<<<dim3(BATCH, N / BM), dim3(256), 0, stream>>>(q, o, khi, klo, vf);
}